// Round 7
// baseline (2029.554 us; speedup 1.0000x reference)
//
#include <hip/hip_runtime.h>
#include <hip/hip_bf16.h>

#define NSITES 256
#define NM 128        // nup == ndn
#define NMODES 512

typedef unsigned long long u64;
typedef unsigned int u32;

#define REP4(M)    M(0) M(1) M(2) M(3)
#define REP8(M)    M(0) M(1) M(2) M(3) M(4) M(5) M(6) M(7)
#define REP4P(M,P) M(0,P) M(1,P) M(2,P) M(3,P)
#define REP8P(M,P) M(0,P) M(1,P) M(2,P) M(3,P) M(4,P) M(5,P) M(6,P) M(7,P)

// DPP max-reduce step: all-VALU cross-lane.
template<int CTRL>
__device__ __forceinline__ float dpp_max(float x) {
  const int xi = __float_as_int(x);
  const int yi = __builtin_amdgcn_update_dpp(xi, xi, CTRL, 0xF, 0xF, false);
  return fmaxf(x, __int_as_float(yi));
}
// Wave-wide max of x, broadcast to all lanes.
__device__ __forceinline__ float wave_max(float x) {
  x = dpp_max<0x128>(x);   // row_ror:8
  x = dpp_max<0x124>(x);   // row_ror:4
  x = dpp_max<0x122>(x);   // row_ror:2
  x = dpp_max<0x121>(x);   // row_ror:1
  x = dpp_max<0x142>(x);   // row_bcast15
  x = dpp_max<0x143>(x);   // row_bcast31 -> lane 63 has global max
  return __int_as_float(__builtin_amdgcn_readlane(__float_as_int(x), 63));
}
// Read element p (0..127) of a column stored as (x1: rows 0..63, x2: 64..127).
__device__ __forceinline__ float rl2(float x1, float x2, int p) {
  const int v1 = __builtin_amdgcn_readlane(__float_as_int(x1), p & 63);
  const int v2 = __builtin_amdgcn_readlane(__float_as_int(x2), p & 63);
  return __int_as_float(p < 64 ? v1 : v2);
}

// One block per (batch, spin). 512 threads, register-resident 128x128 LU with
// partial pivoting, pivot-retirement (no physical swaps), ONE barrier/column.
// Thread (tx,ty), tx=t&15, ty=t>>4 (0..31), owns a[II][JJ] = A[II*32+ty][JJ*16+tx]
// (II<4, JJ<8 -> 32 floats/thread; half of round 5's 64 -> lower VGPR, higher
// occupancy, half the per-wave update issue). Every wave holds a full copy of
// the current pivot column in (c1,c2) -> argmax is LDS-free (DPP butterfly).
// Column k+1 is maintained one step ahead in regs; col k+2 published to a
// parity-alternating colbuf. Pivot rows retire in place (flags r1,r2); sign =
// pivot signs XOR parity(inversions of ipiv), counted at the end.
// ALL register indices are preprocessor literals (SROA runs before unrolling).
__global__ __launch_bounds__(512, 4) void lu_kernel(
    const int* __restrict__ n, const float* __restrict__ phi_up,
    const float* __restrict__ phi_dn, float* __restrict__ ws, int B)
{
  __shared__ int occ[NSITES];
  __shared__ int wcnt[8];
  __shared__ float colbuf[2][NM];
  __shared__ float rowP[2][NM];
  __shared__ int ipiv[NM];

  const int t = threadIdx.x;
  const int tx = t & 15, ty = t >> 4;
  const int lane = t & 63, wv = t >> 6;
  const int bs = blockIdx.x;
  const int b = bs >> 1, spin = bs & 1;
  const int* nn = n + b * NMODES + spin * NSITES;
  const float* phi = spin ? phi_dn : phi_up;

  // ---- occupied-site list (exactly NM entries, ascending) ----
  {
    int v = (t < NSITES) ? nn[t] : 0;
    u64 m = __ballot(v != 0);
    if (lane == 0) wcnt[wv] = __popcll(m);
    __syncthreads();
    int off = 0;
    for (int w = 0; w < wv; ++w) off += wcnt[w];
    if (v) occ[off + __popcll(m & ((1ull << lane) - 1))] = t;
    __syncthreads();
  }

  // ---- gather matrix into registers (static indices only) ----
  float a[4][8];
#define GATH(II) { const float* pr_ = phi + occ[(II)*32 + ty] * NM; \
  a[II][0] = pr_[0*16+tx]; a[II][1] = pr_[1*16+tx]; \
  a[II][2] = pr_[2*16+tx]; a[II][3] = pr_[3*16+tx]; \
  a[II][4] = pr_[4*16+tx]; a[II][5] = pr_[5*16+tx]; \
  a[II][6] = pr_[6*16+tx]; a[II][7] = pr_[7*16+tx]; }
  REP4(GATH)
#undef GATH

  // ---- prologue: col 0 -> colbuf[0], col 1 -> colbuf[1] ----
#define PUBP(II, DST) DST[(II)*32 + ty] = a[II][0];
  if (tx == 0) { float* d_ = &colbuf[0][0]; REP4P(PUBP, d_) }
  if (tx == 1) { float* d_ = &colbuf[1][0]; REP4P(PUBP, d_) }
#undef PUBP
  __syncthreads();

  float c1 = colbuf[0][lane];
  float c2 = colbuf[0][lane + 64];
  int r1 = 0, r2 = 0;           // retirement flags for rows lane, lane+64
  float l2sum = 0.f;
  int sb = 0;
  const int bidxA = (ty) << 2;        // bpermute byte-index: rows II*32+ty
  const int bidxB = (32 + ty) << 2;   // II even/odd half within c1 or c2

  for (int k = 0; k < NM; ++k) {
    const int cur = k & 1;

    // ================= P1 (pre-barrier): argmax + stage pivot row ==========
    const float ca1 = r1 ? -1.0f : fabsf(c1);
    const float ca2 = r2 ? -1.0f : fabsf(c2);
    const float mx = wave_max(fmaxf(ca1, ca2));
    const u64 b1m = __ballot(ca1 == mx);
    const u64 b2m = __ballot(ca2 == mx);
    int p = b1m ? (__ffsll(b1m) - 1) : (__ffsll(b2m) + 63);
    p = __builtin_amdgcn_readfirstlane(p);
    const float pivv = rl2(c1, c2, p);
    const float rpiv = __builtin_amdgcn_rcpf(pivv);
    r1 |= (p == lane);
    r2 |= (p == lane + 64);
    const float m1 = r1 ? 0.f : c1 * rpiv;   // retired + pivot rows -> m = 0
    const float m2 = r2 ? 0.f : c2 * rpiv;

    // stage pivot row (updated through k-1: the finished U row)
    if (ty == (p & 31)) {
      float* d_ = &rowP[cur][0];
      switch (p >> 5) {
#define SRP(II) case II: \
  d_[0*16+tx]=a[II][0]; d_[1*16+tx]=a[II][1]; d_[2*16+tx]=a[II][2]; d_[3*16+tx]=a[II][3]; \
  d_[4*16+tx]=a[II][4]; d_[5*16+tx]=a[II][5]; d_[6*16+tx]=a[II][6]; d_[7*16+tx]=a[II][7]; break;
        REP4(SRP)
#undef SRP
      }
    }
    if (t == 0) ipiv[k] = p;
    l2sum += __log2f(mx);
    sb ^= (int)(__float_as_uint(pivv) >> 31);

    __syncthreads();  // single barrier per column

    // ================= P2 (post-barrier): update ===========================
    if (k < NM - 1) {
      // multipliers for my 4 rows via wave-local bpermute
      float mI[4];
      mI[0] = __int_as_float(__builtin_amdgcn_ds_bpermute(bidxA, __float_as_int(m1)));
      mI[1] = __int_as_float(__builtin_amdgcn_ds_bpermute(bidxB, __float_as_int(m1)));
      mI[2] = __int_as_float(__builtin_amdgcn_ds_bpermute(bidxA, __float_as_int(m2)));
      mI[3] = __int_as_float(__builtin_amdgcn_ds_bpermute(bidxB, __float_as_int(m2)));

      // rank-1 update of columns >= k+1 (block-trimmed)
      const int T = (k + 1) >> 4;
      float pr[8];
#define PRE(JJ, KB) if ((JJ) >= (KB)) pr[JJ] = rowP[cur][(JJ)*16 + tx];
#define UPDROW(II, KB) { \
  if (0 >= (KB)) a[II][0] = fmaf(-mI[II], pr[0], a[II][0]); \
  if (1 >= (KB)) a[II][1] = fmaf(-mI[II], pr[1], a[II][1]); \
  if (2 >= (KB)) a[II][2] = fmaf(-mI[II], pr[2], a[II][2]); \
  if (3 >= (KB)) a[II][3] = fmaf(-mI[II], pr[3], a[II][3]); \
  if (4 >= (KB)) a[II][4] = fmaf(-mI[II], pr[4], a[II][4]); \
  if (5 >= (KB)) a[II][5] = fmaf(-mI[II], pr[5], a[II][5]); \
  if (6 >= (KB)) a[II][6] = fmaf(-mI[II], pr[6], a[II][6]); \
  if (7 >= (KB)) a[II][7] = fmaf(-mI[II], pr[7], a[II][7]); }
#define LUCASE(KB) case KB: { REP8P(PRE, KB) REP4P(UPDROW, KB) } break;
      switch (T) {
        REP8(LUCASE)
      }
#undef LUCASE
#undef UPDROW
#undef PRE

      // column k+1 (from colbuf: through k-1) -> bring through k in regs
      float d1 = colbuf[cur ^ 1][lane];
      float d2 = colbuf[cur ^ 1][lane + 64];
      const float ud = rl2(d1, d2, p);
      c1 = fmaf(-m1, ud, d1);
      c2 = fmaf(-m2, ud, d2);

      // publish column k+2 (now through k) into colbuf[cur]
      if (k < NM - 2) {
        const int cn = k + 2;
        if (tx == (cn & 15)) {
          float* dst = &colbuf[cur][0];
          switch (cn >> 4) {
#define PUBJ(JJ) case JJ: \
  dst[0*32+ty]=a[0][JJ]; dst[1*32+ty]=a[1][JJ]; \
  dst[2*32+ty]=a[2][JJ]; dst[3*32+ty]=a[3][JJ]; break;
            REP8(PUBJ)
#undef PUBJ
          }
        }
      }
    }
  }

  // ---- permutation parity from pivot sequence (inversion count) ----
  __syncthreads();
  int inv = 0;
  if (t < NM) {
    const int my = ipiv[t];
    for (int l = t + 1; l < NM; ++l) inv += (my > ipiv[l]) ? 1 : 0;
  }
  const u64 bal = __ballot((t < NM) && (inv & 1));
  if (lane == 0) wcnt[wv] = __popcll(bal);
  __syncthreads();

  if (t == 0) {
    int par = 0;
    for (int w = 0; w < 8; ++w) par += wcnt[w];
    const int s = (sb ^ par) & 1;
    ws[B + spin * B + b] = l2sum * 0.6931471805599453f;   // logabs: [B, 3B)
    ws[3 * B + spin * B + b] = s ? -1.f : 1.f;            // sign:   [3B, 5B)
  }
}

// One block per batch: log_j = -0.5 * sum_{i occ} sum_c v[i][c] * nf[c]
__global__ __launch_bounds__(256) void jastrow_kernel(
    const int* __restrict__ n, const float* __restrict__ v,
    float* __restrict__ ws, int B)
{
  __shared__ int occ[256];
  __shared__ float nf[NMODES];
  __shared__ int wcnt[8];
  __shared__ float red[256];
  const int t = threadIdx.x, b = blockIdx.x;
  const int lane = t & 63, wv = t >> 6;
  const int* nn = n + b * NMODES;
  int v0 = nn[t], v1 = nn[256 + t];
  nf[t] = (float)v0;
  nf[256 + t] = (float)v1;
  u64 m0 = __ballot(v0 != 0), m1 = __ballot(v1 != 0);
  if (lane == 0) { wcnt[wv] = __popcll(m0); wcnt[4 + wv] = __popcll(m1); }
  __syncthreads();
  int off0 = 0;
  for (int w = 0; w < wv; ++w) off0 += wcnt[w];
  int base1 = wcnt[0] + wcnt[1] + wcnt[2] + wcnt[3];
  int off1 = base1;
  for (int w = 0; w < wv; ++w) off1 += wcnt[4 + w];
  if (v0) occ[off0 + __popcll(m0 & ((1ull << lane) - 1))] = t;
  if (v1) occ[off1 + __popcll(m1 & ((1ull << lane) - 1))] = 256 + t;
  __syncthreads();

  float acc = 0.f;
  for (int r = wv * 64; r < wv * 64 + 64; ++r) {
    const float* row = v + occ[r] * NMODES;   // occ[r] wave-uniform -> broadcast
#pragma unroll
    for (int cc = 0; cc < 8; ++cc) {
      int c = cc * 64 + lane;                 // coalesced 256B per iter
      acc += row[c] * nf[c];
    }
  }
  red[t] = acc;
  __syncthreads();
  for (int s = 128; s >= 1; s >>= 1) {
    if (t < s) red[t] += red[t + s];
    __syncthreads();
  }
  if (t == 0) ws[b] = -0.5f * red[0];
}

__global__ void finalize_kernel(const float* __restrict__ ws,
                                float* __restrict__ out, int B)
{
  int b = blockIdx.x * 256 + threadIdx.x;
  if (b < B) {
    float lj = ws[b];
    float la_u = ws[B + b], la_d = ws[2 * B + b];
    float s_u = ws[3 * B + b], s_d = ws[4 * B + b];
    out[b] = s_u * s_d;
    out[B + b] = lj + la_u + la_d;
  }
}

extern "C" void kernel_launch(void* const* d_in, const int* in_sizes, int n_in,
                              void* d_out, int out_size, void* d_ws, size_t ws_size,
                              hipStream_t stream) {
  const int* n = (const int*)d_in[0];
  const float* phi_up = (const float*)d_in[1];
  const float* phi_dn = (const float*)d_in[2];
  const float* v = (const float*)d_in[3];
  float* out = (float*)d_out;
  float* ws = (float*)d_ws;
  const int B = in_sizes[0] / NMODES;  // 4096

  jastrow_kernel<<<B, 256, 0, stream>>>(n, v, ws, B);
  lu_kernel<<<2 * B, 512, 0, stream>>>(n, phi_up, phi_dn, ws, B);
  finalize_kernel<<<(B + 255) / 256, 256, 0, stream>>>(ws, out, B);
}